// Round 5
// baseline (140.013 us; speedup 1.0000x reference)
//
#include <hip/hip_runtime.h>
#include <hip/hip_bf16.h>
#include <math.h>

#define B_   4
#define C_   64
#define N_   4096
#define CQK_ 16
#define L2E  1.4426950408889634f

typedef __attribute__((ext_vector_type(8))) short bf16x8;
typedef __attribute__((ext_vector_type(4))) float f32x4;

#define MFMA16(a, b, c) __builtin_amdgcn_mfma_f32_16x16x32_bf16(a, b, c, 0, 0, 0)

static __device__ inline ushort f2bf(float f) {
    __hip_bfloat16 h = __float2bfloat16(f);
    return *reinterpret_cast<ushort*>(&h);
}
static __device__ inline uint packbf(float a, float b) {
    return (uint)f2bf(a) | ((uint)f2bf(b) << 16);
}

// ---------------- QKV projection, MFMA with 2-way k-split ----------------
// OUT[96,N] = W[96,64] @ X[64,N]; rows 0-15=Q (xrgb, xL2E), 16-31=K, 32-95=V.
// Block: 256 thr = 4 waves = (pw pixel-half) x (cw channel-half). Each wave:
// one k=32 MFMA per out-tile (6), partials summed through LDS.
// Grid 512 blocks -> 2048 waves (2/SIMD), ~40KB LDS.
__global__ __launch_bounds__(256) void qkv_mfma(
    const float* __restrict__ x, const float* __restrict__ xrgb,
    const float* __restrict__ Wq, const float* __restrict__ bq,
    const float* __restrict__ Wk, const float* __restrict__ bk,
    const float* __restrict__ Wv, const float* __restrict__ bv,
    ushort* __restrict__ Qo, ushort* __restrict__ Ko, ushort* __restrict__ Vo)
{
    __shared__ ushort WL[96 * 66];       // bf16 weights (row pad 66)
    __shared__ float  BLs[96];
    __shared__ float  OP[2][96][33];     // per-cw partials [cw][out_ch][px]

    const int t = threadIdx.x;
    const int b = blockIdx.y;
    const int n0 = blockIdx.x * 32;
    const int w = t >> 6, lane = t & 63, li = lane & 15, g = lane >> 4;
    const int pw = w & 1, cw = w >> 1;

    for (int idx = t; idx < 96 * 64; idx += 256) {
        const int row = idx >> 6, col = idx & 63;
        float v;
        if (row < 16)      v = Wq[row * 64 + col] * L2E;   // fold log2e into Q
        else if (row < 32) v = Wk[(row - 16) * 64 + col];
        else               v = Wv[(row - 32) * 64 + col];
        WL[row * 66 + col] = f2bf(v);
    }
    if (t < 96)
        BLs[t] = (t < 16) ? bq[t] * L2E : (t < 32 ? bk[t - 16] : bv[t - 32]);
    __syncthreads();

    // B-fragment: pixel n (col=li), channels c0..c0+7 (k = g*8+r)
    const int n = n0 + pw * 16 + li;
    const int c0 = cw * 32 + g * 8;
    const float* xb = x    + ((size_t)b * C_ + c0) * N_ + n;
    const float* rb = xrgb + ((size_t)b * C_ + c0) * N_ + n;
    bf16x8 bx, br;
    #pragma unroll
    for (int r = 0; r < 8; ++r) {
        bx[r] = (short)f2bf(xb[(size_t)r * N_]);
        br[r] = (short)f2bf(rb[(size_t)r * N_]);
    }

    const f32x4 cz = {0.f, 0.f, 0.f, 0.f};
    #pragma unroll
    for (int ot = 0; ot < 6; ++ot) {
        const bf16x8 wa = *(const bf16x8*)&WL[(ot * 16 + li) * 66 + cw * 32 + g * 8];
        const f32x4 acc = MFMA16(wa, (ot == 0 ? br : bx), cz);
        #pragma unroll
        for (int r = 0; r < 4; ++r)
            OP[cw][ot * 16 + g * 4 + r][pw * 16 + li] = acc[r];
    }
    __syncthreads();

    // combine halves + bias, convert, store
    {   // Q and K: 32 px x 8 channel-pairs
        const int p = t >> 3, cp = t & 7;
        const float q0 = OP[0][cp * 2][p]     + OP[1][cp * 2][p]     + BLs[cp * 2];
        const float q1 = OP[0][cp * 2 + 1][p] + OP[1][cp * 2 + 1][p] + BLs[cp * 2 + 1];
        *(uint*)&Qo[(size_t)(b * N_ + n0 + p) * 16 + cp * 2] = packbf(q0, q1);
        const float k0 = OP[0][16 + cp * 2][p]     + OP[1][16 + cp * 2][p]     + BLs[16 + cp * 2];
        const float k1 = OP[0][16 + cp * 2 + 1][p] + OP[1][16 + cp * 2 + 1][p] + BLs[16 + cp * 2 + 1];
        *(uint*)&Ko[(size_t)(b * N_ + n0 + p) * 16 + cp * 2] = packbf(k0, k1);
    }
    {   // V: 64 ch x 4 pixel-octets
        const int ch = t >> 2, po = (t & 3) * 8;
        const float bs = BLs[32 + ch];
        uint4 o;
        #pragma unroll
        for (int e = 0; e < 4; ++e) {
            const float v0 = OP[0][32 + ch][po + 2 * e]     + OP[1][32 + ch][po + 2 * e]     + bs;
            const float v1 = OP[0][32 + ch][po + 2 * e + 1] + OP[1][32 + ch][po + 2 * e + 1] + bs;
            ((uint*)&o)[e] = packbf(v0, v1);
        }
        *(uint4*)&Vo[(size_t)(b * C_ + ch) * N_ + n0 + po] = o;
    }
}

// ---------------- fused flash attention, 8-way j-split ----------------
// 1024 threads = 16 waves = (jgl 0..7) x (wq 0..1). Block owns 32 queries;
// each jgl owns N/8=512 keys in 16 chunks of 32. Partials merged in LDS.
// Grid 512 blocks, LDS 67584 -> with VGPR<=64, 2 blocks/CU = 8 waves/SIMD.
// launch_bounds min-waves kept at 4: R4's (1024,8) squeezed VGPR to 32 and
// spilled in the hot loop (dur 3x). HW co-residency comes from actual VGPR.
#define SMEM_BYTES 67584
__global__ __launch_bounds__(1024, 4) void flash_attn_mfma(
    const ushort* __restrict__ Qg, const ushort* __restrict__ Kg,
    const ushort* __restrict__ Vg, const float* __restrict__ x,
    const float* __restrict__ lam, float* __restrict__ out)
{
    __shared__ __align__(16) char smem[SMEM_BYTES];
    ushort* KL = (ushort*)smem;              // [8][32][24]  12288 B
    ushort* VL = (ushort*)(smem + 12288);    // [8][64][34]  34816 B
    ushort* PL = (ushort*)(smem + 47104);    // [16][16][36] 18432 B
    // combine overlay (only after main loop's final barrier):
    float*  OC = (float*)smem;               // [2][8][64][16] 65536 B
    float*  MC = (float*)(smem + 65536);     // [2][8][16]
    float*  LC = (float*)(smem + 66560);     // [2][8][16]

    const int t    = threadIdx.x;
    const int w    = t >> 6;
    const int lane = t & 63;
    const int li   = lane & 15;
    const int g    = lane >> 4;
    const int jgl  = w >> 1;
    const int wq   = w & 1;
    const int b    = blockIdx.y;
    const int i0   = blockIdx.x * 32;
    const int iq0  = i0 + wq * 16;

    const bf16x8 fz = {0, 0, 0, 0, 0, 0, 0, 0};
    const f32x4  cz = {0.f, 0.f, 0.f, 0.f};

    // Q fragment (B operand: col=i=li, k=c=g*8+r; g>=2 zero-pads k 16->32)
    bf16x8 qf = fz;
    if (g < 2)
        qf = *(const bf16x8*)(Qg + ((size_t)(b * N_ + iq0 + li) * 16 + g * 8));

    float m_run = -1e30f, l_run = 0.f;
    f32x4 oacc[4];
    #pragma unroll
    for (int ct = 0; ct < 4; ++ct) oacc[ct] = cz;

    // staging: each jg's 128 threads stage its 32-key chunk
    const int tg = t & 127;
    const int kr = tg >> 2, ks = (tg & 3) * 4;      // K: 32 rows x 4 segs x 8B
    const int vr = tg >> 1, vs = (tg & 1) * 16;     // V: 64 ch x 2 segs x 32B
    const size_t jbase = (size_t)jgl * (N_ / 8);
    const ushort* ksrc = Kg + ((size_t)(b * N_) + jbase + kr) * 16 + ks;
    const ushort* vsrc = Vg + (size_t)(b * C_ + vr) * N_ + jbase + vs;
    ushort* klw = KL + (jgl * 32 + kr) * 24 + ks;
    ushort* vlw = VL + (jgl * 64 + vr) * 34 + vs;

    // prologue: stage chunk 0
    ushort4 kreg  = *(const ushort4*)(ksrc);
    uint4   vreg0 = *(const uint4*)(vsrc);
    uint4   vreg1 = *(const uint4*)(vsrc + 8);
    *(ushort4*)klw = kreg;
    *(uint4*)vlw = vreg0;
    *(uint4*)(vlw + 8) = vreg1;

    for (int jc = 0; jc < 16; ++jc) {
        __syncthreads();   // staged chunk jc visible

        if (jc + 1 < 16) {   // register prefetch of next chunk (T14)
            const size_t jn = (size_t)(jc + 1) * 32;
            kreg  = *(const ushort4*)(ksrc + jn * 16);
            vreg0 = *(const uint4*)(vsrc + jn);
            vreg1 = *(const uint4*)(vsrc + jn + 8);
        }

        // ---- energy: S^T[j][i] = sum_c K[j][c] Q[i][c]  (j = jt*16+4g+r) ----
        f32x4 st[2];
        #pragma unroll
        for (int jt = 0; jt < 2; ++jt) {
            const bf16x8 kf = *(const bf16x8*)(KL + (jgl * 32 + jt * 16 + li) * 24 + (g & 1) * 8);
            st[jt] = MFMA16(kf, qf, cz);   // k>=16 products vanish via qf zeros
        }

        // ---- online softmax (8 vals/lane), defer-rescale (T13) ----
        float m_c = fmaxf(fmaxf(fmaxf(st[0][0], st[0][1]), fmaxf(st[0][2], st[0][3])),
                          fmaxf(fmaxf(st[1][0], st[1][1]), fmaxf(st[1][2], st[1][3])));
        m_c = fmaxf(m_c, __shfl_xor(m_c, 16));
        m_c = fmaxf(m_c, __shfl_xor(m_c, 32));
        if (__any(m_c > m_run + 8.f)) {
            const float m_new = fmaxf(m_run, m_c);
            const float sc = exp2f(m_run - m_new);
            l_run *= sc;
            #pragma unroll
            for (int ct = 0; ct < 4; ++ct) {
                oacc[ct][0] *= sc; oacc[ct][1] *= sc;
                oacc[ct][2] *= sc; oacc[ct][3] *= sc;
            }
            m_run = m_new;
        }
        float psum = 0.f;
        #pragma unroll
        for (int jt = 0; jt < 2; ++jt)
            #pragma unroll
            for (int r = 0; r < 4; ++r) {
                const float p = exp2f(st[jt][r] - m_run);
                st[jt][r] = p;
                psum += p;
            }
        psum += __shfl_xor(psum, 16);
        psum += __shfl_xor(psum, 32);
        l_run += psum;

        // ---- P -> bf16 -> per-wave LDS (row i=li, col j = jt*16+g*4+r) ----
        #pragma unroll
        for (int jt = 0; jt < 2; ++jt) {
            uint2 pw;
            pw.x = packbf(st[jt][0], st[jt][1]);
            pw.y = packbf(st[jt][2], st[jt][3]);
            *(uint2*)(PL + (w * 16 + li) * 36 + jt * 16 + g * 4) = pw;
        }

        // ---- PV: O^T[c][i] += sum_j V[c][j] P^T[j][i]  (k = j = 32 exact) ----
        const bf16x8 pf = *(const bf16x8*)(PL + (w * 16 + li) * 36 + g * 8);
        #pragma unroll
        for (int ct = 0; ct < 4; ++ct) {
            const bf16x8 vf = *(const bf16x8*)(VL + (jgl * 64 + ct * 16 + li) * 34 + g * 8);
            oacc[ct] = MFMA16(vf, pf, oacc[ct]);
        }

        __syncthreads();   // all waves done reading KL/VL/PL

        if (jc + 1 < 16) {   // write prefetched chunk
            *(ushort4*)klw = kreg;
            *(uint4*)vlw = vreg0;
            *(uint4*)(vlw + 8) = vreg1;
        }
    }

    // ---- write partials into combine overlay ----
    #pragma unroll
    for (int ct = 0; ct < 4; ++ct)
        #pragma unroll
        for (int r = 0; r < 4; ++r)
            OC[((wq * 8 + jgl) * 64 + ct * 16 + g * 4 + r) * 16 + li] = oacc[ct][r];
    if (g == 0) {
        MC[(wq * 8 + jgl) * 16 + li] = m_run;
        LC[(wq * 8 + jgl) * 16 + li] = l_run;
    }
    __syncthreads();

    // ---- merge 8 j-partials; wave (wq,jgl) -> queries wq, channels jgl*8..+8
    float mp[8], lp[8];
    #pragma unroll
    for (int p = 0; p < 8; ++p) {
        mp[p] = MC[(wq * 8 + p) * 16 + li];
        lp[p] = LC[(wq * 8 + p) * 16 + li];
    }
    float ms = mp[0];
    #pragma unroll
    for (int p = 1; p < 8; ++p) ms = fmaxf(ms, mp[p]);
    float wt[8], lsum = 0.f;
    #pragma unroll
    for (int p = 0; p < 8; ++p) { wt[p] = exp2f(mp[p] - ms); lsum += wt[p] * lp[p]; }
    const float inv = lam[0] / lsum;
    const int n = i0 + wq * 16 + li;
    #pragma unroll
    for (int d = 0; d < 2; ++d) {
        const int c = jgl * 8 + g * 2 + d;
        float ov = 0.f;
        #pragma unroll
        for (int p = 0; p < 8; ++p)
            ov += wt[p] * OC[((wq * 8 + p) * 64 + c) * 16 + li];
        const size_t off = (size_t)(b * C_ + c) * N_ + n;
        out[off] = ov * inv + x[off];
    }
}

extern "C" void kernel_launch(void* const* d_in, const int* in_sizes, int n_in,
                              void* d_out, int out_size, void* d_ws, size_t ws_size,
                              hipStream_t stream)
{
    (void)in_sizes; (void)n_in; (void)out_size; (void)ws_size;
    const float* x    = (const float*)d_in[0];
    const float* xrgb = (const float*)d_in[1];
    const float* Wq   = (const float*)d_in[2];
    const float* bq   = (const float*)d_in[3];
    const float* Wk   = (const float*)d_in[4];
    const float* bk   = (const float*)d_in[5];
    const float* Wv   = (const float*)d_in[6];
    const float* bv   = (const float*)d_in[7];
    const float* lam  = (const float*)d_in[8];
    float* out = (float*)d_out;

    // workspace (bf16): Q 512KB | K 512KB | V 2MB — all fully overwritten
    ushort* Qw = (ushort*)d_ws;                       // [B][N][16]
    ushort* Kw = Qw + (size_t)B_ * N_ * CQK_;         // [B][N][16]
    ushort* Vw = Kw + (size_t)B_ * N_ * CQK_;         // [B][C][N]

    qkv_mfma<<<dim3(N_ / 32, B_), 256, 0, stream>>>(
        x, xrgb, Wq, bq, Wk, bk, Wv, bv, Qw, Kw, Vw);

    flash_attn_mfma<<<dim3(N_ / 32, B_), 1024, 0, stream>>>(
        Qw, Kw, Vw, x, lam, out);
}

// Round 6
// 85.284 us; speedup vs baseline: 1.6417x; 1.6417x over previous
//
#include <hip/hip_runtime.h>
#include <hip/hip_bf16.h>
#include <math.h>

#define B_   4
#define C_   64
#define N_   4096
#define CQK_ 16
#define L2E  1.4426950408889634f

typedef __attribute__((ext_vector_type(8))) short bf16x8;
typedef __attribute__((ext_vector_type(4))) float f32x4;

#define MFMA16(a, b, c) __builtin_amdgcn_mfma_f32_16x16x32_bf16(a, b, c, 0, 0, 0)

static __device__ inline ushort f2bf(float f) {
    __hip_bfloat16 h = __float2bfloat16(f);
    return *reinterpret_cast<ushort*>(&h);
}
static __device__ inline uint packbf(float a, float b) {
    return (uint)f2bf(a) | ((uint)f2bf(b) << 16);
}

// ---------------- QKV projection, MFMA with 2-way k-split ----------------
// (unchanged from R5: ~12us, 2 waves/SIMD)
__global__ __launch_bounds__(256) void qkv_mfma(
    const float* __restrict__ x, const float* __restrict__ xrgb,
    const float* __restrict__ Wq, const float* __restrict__ bq,
    const float* __restrict__ Wk, const float* __restrict__ bk,
    const float* __restrict__ Wv, const float* __restrict__ bv,
    ushort* __restrict__ Qo, ushort* __restrict__ Ko, ushort* __restrict__ Vo)
{
    __shared__ ushort WL[96 * 66];       // bf16 weights (row pad 66)
    __shared__ float  BLs[96];
    __shared__ float  OP[2][96][33];     // per-cw partials [cw][out_ch][px]

    const int t = threadIdx.x;
    const int b = blockIdx.y;
    const int n0 = blockIdx.x * 32;
    const int w = t >> 6, lane = t & 63, li = lane & 15, g = lane >> 4;
    const int pw = w & 1, cw = w >> 1;

    for (int idx = t; idx < 96 * 64; idx += 256) {
        const int row = idx >> 6, col = idx & 63;
        float v;
        if (row < 16)      v = Wq[row * 64 + col] * L2E;   // fold log2e into Q
        else if (row < 32) v = Wk[(row - 16) * 64 + col];
        else               v = Wv[(row - 32) * 64 + col];
        WL[row * 66 + col] = f2bf(v);
    }
    if (t < 96)
        BLs[t] = (t < 16) ? bq[t] * L2E : (t < 32 ? bk[t - 16] : bv[t - 32]);
    __syncthreads();

    // B-fragment: pixel n (col=li), channels c0..c0+7 (k = g*8+r)
    const int n = n0 + pw * 16 + li;
    const int c0 = cw * 32 + g * 8;
    const float* xb = x    + ((size_t)b * C_ + c0) * N_ + n;
    const float* rb = xrgb + ((size_t)b * C_ + c0) * N_ + n;
    bf16x8 bx, br;
    #pragma unroll
    for (int r = 0; r < 8; ++r) {
        bx[r] = (short)f2bf(xb[(size_t)r * N_]);
        br[r] = (short)f2bf(rb[(size_t)r * N_]);
    }

    const f32x4 cz = {0.f, 0.f, 0.f, 0.f};
    #pragma unroll
    for (int ot = 0; ot < 6; ++ot) {
        const bf16x8 wa = *(const bf16x8*)&WL[(ot * 16 + li) * 66 + cw * 32 + g * 8];
        const f32x4 acc = MFMA16(wa, (ot == 0 ? br : bx), cz);
        #pragma unroll
        for (int r = 0; r < 4; ++r)
            OP[cw][ot * 16 + g * 4 + r][pw * 16 + li] = acc[r];
    }
    __syncthreads();

    // combine halves + bias, convert, store
    {   // Q and K: 32 px x 8 channel-pairs
        const int p = t >> 3, cp = t & 7;
        const float q0 = OP[0][cp * 2][p]     + OP[1][cp * 2][p]     + BLs[cp * 2];
        const float q1 = OP[0][cp * 2 + 1][p] + OP[1][cp * 2 + 1][p] + BLs[cp * 2 + 1];
        *(uint*)&Qo[(size_t)(b * N_ + n0 + p) * 16 + cp * 2] = packbf(q0, q1);
        const float k0 = OP[0][16 + cp * 2][p]     + OP[1][16 + cp * 2][p]     + BLs[16 + cp * 2];
        const float k1 = OP[0][16 + cp * 2 + 1][p] + OP[1][16 + cp * 2 + 1][p] + BLs[16 + cp * 2 + 1];
        *(uint*)&Ko[(size_t)(b * N_ + n0 + p) * 16 + cp * 2] = packbf(k0, k1);
    }
    {   // V: 64 ch x 4 pixel-octets
        const int ch = t >> 2, po = (t & 3) * 8;
        const float bs = BLs[32 + ch];
        uint4 o;
        #pragma unroll
        for (int e = 0; e < 4; ++e) {
            const float v0 = OP[0][32 + ch][po + 2 * e]     + OP[1][32 + ch][po + 2 * e]     + bs;
            const float v1 = OP[0][32 + ch][po + 2 * e + 1] + OP[1][32 + ch][po + 2 * e + 1] + bs;
            ((uint*)&o)[e] = packbf(v0, v1);
        }
        *(uint4*)&Vo[(size_t)(b * C_ + ch) * N_ + n0 + po] = o;
    }
}

// ---------------- flash attention, barrier-free main loop ----------------
// K+V per batch = 640KB bf16 -> L2-resident per XCD; read MFMA fragments
// DIRECTLY from global (no K/V LDS staging, no main-loop barriers).
// 512 thr = 8 waves = (jg 0..3) x (wq 0..1); block owns 32 queries; each
// wave flashes its 16 queries over jg's N/4=1024 keys (16 chunks of 64).
// P: per-wave-private LDS (no barrier). End: 4-way partial merge in LDS.
// LDS 35840B -> 3-4 blocks/CU; VGPR capped 84 by (512,6).
#define SMEM_BYTES 35840
__global__ __launch_bounds__(512, 6) void flash_attn_mfma(
    const ushort* __restrict__ Qg, const ushort* __restrict__ Kg,
    const ushort* __restrict__ Vg, const float* __restrict__ x,
    const float* __restrict__ lam, float* __restrict__ out)
{
    __shared__ __align__(16) char smem[SMEM_BYTES];
    ushort* PL = (ushort*)smem;              // [8][16][66]  16896 B (main loop)
    // combine overlay (used only after the post-loop barrier):
    float*  OC = (float*)smem;               // [2][4][64][17] 34816 B
    float*  MC = (float*)(smem + 34816);     // [2][4][16]
    float*  LC = (float*)(smem + 35328);     // [2][4][16]

    const int t    = threadIdx.x;
    const int w    = t >> 6;
    const int lane = t & 63;
    const int li   = lane & 15;
    const int g    = lane >> 4;
    const int jg   = w >> 1;
    const int wq   = w & 1;
    const int b    = blockIdx.y;
    const int i0   = blockIdx.x * 32;
    const int iq0  = i0 + wq * 16;

    const bf16x8 fz = {0, 0, 0, 0, 0, 0, 0, 0};
    const f32x4  cz = {0.f, 0.f, 0.f, 0.f};

    // Q fragment (B operand: col=i=li, k=c=g*8+r; g>=2 zero-pads k 16->32)
    bf16x8 qf = fz;
    if (g < 2)
        qf = *(const bf16x8*)(Qg + ((size_t)(b * N_ + iq0 + li) * 16 + g * 8));

    float m_run = -1e30f, l_run = 0.f;
    f32x4 oacc[4];
    #pragma unroll
    for (int ct = 0; ct < 4; ++ct) oacc[ct] = cz;

    // per-lane global fragment bases (L2-resident reads)
    const size_t jbase = (size_t)jg * (N_ / 4);
    // kf(jt): K[j = jbase + j0 + jt*16 + li][(g&1)*8 + 0..7]
    const ushort* kp = Kg + ((size_t)(b * N_) + jbase + li) * 16 + (g & 1) * 8;
    // vf(ct,koff): V[c = ct*16 + li][jbase + j0 + koff + g*8 + 0..7]
    const ushort* vp = Vg + ((size_t)(b * C_) + li) * N_ + jbase + g * 8;
    ushort* plp = PL + (w * 16 + li) * 66;   // per-wave private P row

    for (int jc = 0; jc < 16; ++jc) {
        const int j0 = jc * 64;

        // ---- energy: S^T[j][i] = sum_c K[j][c] Q[i][c]  (j = jt*16+g*4+r) ----
        f32x4 st[4];
        #pragma unroll
        for (int jt = 0; jt < 4; ++jt) {
            const bf16x8 kf = *(const bf16x8*)(kp + (size_t)(j0 + jt * 16) * 16);
            st[jt] = MFMA16(kf, qf, cz);   // k>=16 products vanish via qf zeros
        }

        // ---- online softmax (16 vals/lane), defer-rescale (T13) ----
        float m_c = -1e30f;
        #pragma unroll
        for (int jt = 0; jt < 4; ++jt)
            #pragma unroll
            for (int r = 0; r < 4; ++r) m_c = fmaxf(m_c, st[jt][r]);
        m_c = fmaxf(m_c, __shfl_xor(m_c, 16));
        m_c = fmaxf(m_c, __shfl_xor(m_c, 32));
        if (__any(m_c > m_run + 8.f)) {
            const float m_new = fmaxf(m_run, m_c);
            const float sc = exp2f(m_run - m_new);
            l_run *= sc;
            #pragma unroll
            for (int ct = 0; ct < 4; ++ct) {
                oacc[ct][0] *= sc; oacc[ct][1] *= sc;
                oacc[ct][2] *= sc; oacc[ct][3] *= sc;
            }
            m_run = m_new;
        }
        float psum = 0.f;
        #pragma unroll
        for (int jt = 0; jt < 4; ++jt)
            #pragma unroll
            for (int r = 0; r < 4; ++r) {
                const float p = exp2f(st[jt][r] - m_run);
                st[jt][r] = p;
                psum += p;
            }
        psum += __shfl_xor(psum, 16);
        psum += __shfl_xor(psum, 32);
        l_run += psum;

        // ---- P -> bf16 -> per-wave LDS (row i=li, col j = jt*16+g*4+r) ----
        #pragma unroll
        for (int jt = 0; jt < 4; ++jt) {
            uint2 pw;
            pw.x = packbf(st[jt][0], st[jt][1]);
            pw.y = packbf(st[jt][2], st[jt][3]);
            *(uint2*)(plp + jt * 16 + g * 4) = pw;
        }

        // ---- PV: O^T[c][i] += sum_j V[c][j] P^T[j][i] ----
        const bf16x8 pf0 = *(const bf16x8*)(plp + g * 8);
        const bf16x8 pf1 = *(const bf16x8*)(plp + 32 + g * 8);
        #pragma unroll
        for (int ct = 0; ct < 4; ++ct) {
            const bf16x8 vf0 = *(const bf16x8*)(vp + (size_t)ct * 16 * N_ + j0);
            const bf16x8 vf1 = *(const bf16x8*)(vp + (size_t)ct * 16 * N_ + j0 + 32);
            oacc[ct] = MFMA16(vf0, pf0, oacc[ct]);
            oacc[ct] = MFMA16(vf1, pf1, oacc[ct]);
        }
    }

    __syncthreads();   // PL dead everywhere before OC overlay writes

    // ---- write partials into combine overlay ----
    #pragma unroll
    for (int ct = 0; ct < 4; ++ct)
        #pragma unroll
        for (int r = 0; r < 4; ++r)
            OC[((wq * 4 + jg) * 64 + ct * 16 + g * 4 + r) * 17 + li] = oacc[ct][r];
    if (g == 0) {
        MC[(wq * 4 + jg) * 16 + li] = m_run;
        LC[(wq * 4 + jg) * 16 + li] = l_run;
    }
    __syncthreads();

    // ---- merge 4 j-partials; wave (jg,wq) -> queries wq, channels jg*16..+16
    float mp[4], lp[4];
    #pragma unroll
    for (int p = 0; p < 4; ++p) {
        mp[p] = MC[(wq * 4 + p) * 16 + li];
        lp[p] = LC[(wq * 4 + p) * 16 + li];
    }
    float ms = fmaxf(fmaxf(mp[0], mp[1]), fmaxf(mp[2], mp[3]));
    float wt[4], lsum = 0.f;
    #pragma unroll
    for (int p = 0; p < 4; ++p) { wt[p] = exp2f(mp[p] - ms); lsum += wt[p] * lp[p]; }
    const float inv = lam[0] / lsum;
    const int n = i0 + wq * 16 + li;
    #pragma unroll
    for (int r = 0; r < 4; ++r) {
        const int c = jg * 16 + g * 4 + r;
        float ov = 0.f;
        #pragma unroll
        for (int p = 0; p < 4; ++p)
            ov += wt[p] * OC[((wq * 4 + p) * 64 + c) * 17 + li];
        const size_t off = (size_t)(b * C_ + c) * N_ + n;
        out[off] = ov * inv + x[off];
    }
}

extern "C" void kernel_launch(void* const* d_in, const int* in_sizes, int n_in,
                              void* d_out, int out_size, void* d_ws, size_t ws_size,
                              hipStream_t stream)
{
    (void)in_sizes; (void)n_in; (void)out_size; (void)ws_size;
    const float* x    = (const float*)d_in[0];
    const float* xrgb = (const float*)d_in[1];
    const float* Wq   = (const float*)d_in[2];
    const float* bq   = (const float*)d_in[3];
    const float* Wk   = (const float*)d_in[4];
    const float* bk   = (const float*)d_in[5];
    const float* Wv   = (const float*)d_in[6];
    const float* bv   = (const float*)d_in[7];
    const float* lam  = (const float*)d_in[8];
    float* out = (float*)d_out;

    // workspace (bf16): Q 512KB | K 512KB | V 2MB — all fully overwritten
    ushort* Qw = (ushort*)d_ws;                       // [B][N][16]
    ushort* Kw = Qw + (size_t)B_ * N_ * CQK_;         // [B][N][16]
    ushort* Vw = Kw + (size_t)B_ * N_ * CQK_;         // [B][C][N]

    qkv_mfma<<<dim3(N_ / 32, B_), 256, 0, stream>>>(
        x, xrgb, Wq, bq, Wk, bk, Wv, bv, Qw, Kw, Vw);

    flash_attn_mfma<<<dim3(N_ / 32, B_), 512, 0, stream>>>(
        Qw, Kw, Vw, x, lam, out);
}

// Round 7
// 41.832 us; speedup vs baseline: 3.3471x; 2.0387x over previous
//
#include <hip/hip_runtime.h>
#include <hip/hip_bf16.h>
#include <math.h>

#define B_   4
#define C_   64
#define N_   4096
#define L2E  1.4426950408889634f

typedef __attribute__((ext_vector_type(8)))  short bf16x8;
typedef __attribute__((ext_vector_type(4)))  float f32x4;
typedef __attribute__((ext_vector_type(16))) float f32x16;
typedef __attribute__((ext_vector_type(4)))  uint  uint4v;

#define MFMA16(a,b,c) __builtin_amdgcn_mfma_f32_16x16x32_bf16(a,b,c,0,0,0)
#define MFMA32(a,b,c) __builtin_amdgcn_mfma_f32_32x32x16_bf16(a,b,c,0,0,0)

static __device__ inline ushort f2bf(float f) {
    __hip_bfloat16 h = __float2bfloat16(f);
    return *reinterpret_cast<ushort*>(&h);
}
static __device__ inline uint packbf(float a, float b) {
    return (uint)f2bf(a) | ((uint)f2bf(b) << 16);
}
static __device__ inline uint cvtpk(float lo, float hi) {
    uint r;
    asm("v_cvt_pk_bf16_f32 %0, %1, %2" : "=v"(r) : "v"(lo), "v"(hi));
    return r;
}
static __device__ inline void plswap(uint &a, uint &b) {
    asm("v_permlane32_swap_b32 %0, %1" : "+v"(a), "+v"(b));
}

// ---------------- QKV projection: direct-W MFMA, 2-way k-split ----------------
// OUT[96,N] = W[96,64] @ X[64,N]; rows 0-15=Q (xrgb, xL2E), 16-31=K, 32-95=V.
// W/X fragments read straight from global (L2-hot), issued before anything
// else; only one barrier (OP partial combine).
__global__ __launch_bounds__(256) void qkv_mfma(
    const float* __restrict__ x, const float* __restrict__ xrgb,
    const float* __restrict__ Wq, const float* __restrict__ bq,
    const float* __restrict__ Wk, const float* __restrict__ bk,
    const float* __restrict__ Wv, const float* __restrict__ bv,
    ushort* __restrict__ Qo, ushort* __restrict__ Ko, ushort* __restrict__ Vo)
{
    __shared__ float BLs[96];
    __shared__ float OP[2][96][33];

    const int t = threadIdx.x, b = blockIdx.y, n0 = blockIdx.x * 32;
    const int w = t >> 6, lane = t & 63, li = lane & 15, g = lane >> 4;
    const int pw = w & 1, cw = w >> 1;

    // X fragments (early issue, f32)
    const int n = n0 + pw * 16 + li;
    const int c0 = cw * 32 + g * 8;
    const float* xb = x    + ((size_t)b * C_ + c0) * N_ + n;
    const float* rb = xrgb + ((size_t)b * C_ + c0) * N_ + n;
    float fx[8], fr[8];
    #pragma unroll
    for (int r = 0; r < 8; ++r) { fx[r] = xb[(size_t)r * N_]; fr[r] = rb[(size_t)r * N_]; }

    // W fragments direct from global: A row = ot*16+li, cols c0..c0+7
    float wf[6][8];
    #pragma unroll
    for (int ot = 0; ot < 6; ++ot) {
        const float* wsrc;
        if (ot == 0)      wsrc = Wq + li * 64 + c0;
        else if (ot == 1) wsrc = Wk + li * 64 + c0;
        else              wsrc = Wv + ((ot - 2) * 16 + li) * 64 + c0;
        const float4 a = *(const float4*)(wsrc);
        const float4 c = *(const float4*)(wsrc + 4);
        wf[ot][0] = a.x; wf[ot][1] = a.y; wf[ot][2] = a.z; wf[ot][3] = a.w;
        wf[ot][4] = c.x; wf[ot][5] = c.y; wf[ot][6] = c.z; wf[ot][7] = c.w;
    }

    if (t < 96)
        BLs[t] = (t < 16) ? bq[t] * L2E : (t < 32 ? bk[t - 16] : bv[t - 32]);

    bf16x8 bxf, brf;
    #pragma unroll
    for (int r = 0; r < 8; ++r) {
        bxf[r] = (short)f2bf(fx[r]);
        brf[r] = (short)f2bf(fr[r]);
    }

    const f32x4 cz = {0.f, 0.f, 0.f, 0.f};
    #pragma unroll
    for (int ot = 0; ot < 6; ++ot) {
        bf16x8 wa;
        const float s = (ot == 0) ? L2E : 1.0f;   // fold log2e into Q
        #pragma unroll
        for (int r = 0; r < 8; ++r) wa[r] = (short)f2bf(wf[ot][r] * s);
        const f32x4 acc = MFMA16(wa, (ot == 0 ? brf : bxf), cz);
        #pragma unroll
        for (int r = 0; r < 4; ++r)
            OP[cw][ot * 16 + g * 4 + r][pw * 16 + li] = acc[r];
    }
    __syncthreads();

    {   // Q and K: 32 px x 8 channel-pairs
        const int p = t >> 3, cp = t & 7;
        const float q0 = OP[0][cp * 2][p]     + OP[1][cp * 2][p]     + BLs[cp * 2];
        const float q1 = OP[0][cp * 2 + 1][p] + OP[1][cp * 2 + 1][p] + BLs[cp * 2 + 1];
        *(uint*)&Qo[(size_t)(b * N_ + n0 + p) * 16 + cp * 2] = packbf(q0, q1);
        const float k0 = OP[0][16 + cp * 2][p]     + OP[1][16 + cp * 2][p]     + BLs[16 + cp * 2];
        const float k1 = OP[0][16 + cp * 2 + 1][p] + OP[1][16 + cp * 2 + 1][p] + BLs[16 + cp * 2 + 1];
        *(uint*)&Ko[(size_t)(b * N_ + n0 + p) * 16 + cp * 2] = packbf(k0, k1);
    }
    {   // V: 64 ch x 4 pixel-octets
        const int ch = t >> 2, po = (t & 3) * 8;
        const float bs = BLs[32 + ch];
        uint4 o;
        #pragma unroll
        for (int e = 0; e < 4; ++e) {
            const float v0 = OP[0][32 + ch][po + 2 * e]     + OP[1][32 + ch][po + 2 * e]     + bs;
            const float v1 = OP[0][32 + ch][po + 2 * e + 1] + OP[1][32 + ch][po + 2 * e + 1] + bs;
            ((uint*)&o)[e] = packbf(v0, v1);
        }
        *(uint4*)&Vo[(size_t)(b * C_ + ch) * N_ + n0 + po] = o;
    }
}

// ---------------- flash attention, 32x32 MFMA, barrier-free main loop -------
// 512 thr = 8 waves; wave w = j-group w (N/8=512 keys, 16 chunks of 32).
// All 8 waves share the block's 32 queries. Energy: 1x mfma_32x32x16 (K=16
// exact, no padding). P stays in registers: cvt_pk_bf16 + permlane32_swap
// builds the PV B-fragment (mapping derived from the verified C/D layout;
// A/B k-map assumption cancels since vf and pf use the same one).
// V chunk staged in per-wave-PRIVATE LDS slice -> zero main-loop barriers.
// Tail: 2 barriers, partial merge through OT overlay.
#define JG_   8
#define CH_   32
#define NCH_  16           // (N_/JG_)/CH_
#define VROW  40           // 32 j + 8 pad ushorts = 80B rows (16B aligned)
#define OTP   36           // OT row pad (floats), 144B rows (16B aligned)
#define SMEM_FL (73728 + 1056 + 1056 + 128)

__global__ __launch_bounds__(512, 4) void flash32(
    const ushort* __restrict__ Qg, const ushort* __restrict__ Kg,
    const ushort* __restrict__ Vg, const float* __restrict__ x,
    const float* __restrict__ lam, float* __restrict__ out)
{
    __shared__ __align__(16) char smem[SMEM_FL];
    ushort* VL = (ushort*)smem;                      // [8][64][VROW] 40960B
    float*  OT = (float*)smem;                       // [8][64][OTP]  73728B overlay
    float*  MC = (float*)(smem + 73728);             // [8][33]
    float*  LC = (float*)(smem + 73728 + 1056);      // [8][33]
    float*  IV = (float*)(smem + 73728 + 2112);      // [32]

    const int t = threadIdx.x, w = t >> 6, lane = t & 63;
    const int l31 = lane & 31, h = lane >> 5;

    // XCD-locality remap: batch b's 128 blocks land on 2 XCDs (K/V L2-local)
    const int wg = blockIdx.x;                 // grid = 512, 1-D
    const int b  = (wg & 7) >> 1;
    const int it = ((wg >> 3) << 1) | (wg & 1);
    const int i0 = it * 32;

    // Q fragment: B op, col=i=l31, k=c=h*8+r (K=16 exact)
    const bf16x8 qf = *(const bf16x8*)(Qg + ((size_t)(b * N_ + i0 + l31)) * 16 + h * 8);

    const size_t jbase = (size_t)w * (N_ / JG_);
    const ushort* kp = Kg + ((size_t)(b * N_) + jbase + l31) * 16 + h * 8;
    const ushort* vs = Vg + ((size_t)(b * C_) + (lane >> 2)) * N_ + jbase + (lane & 3) * 8;
    ushort* VLw = VL + w * (64 * VROW);
    ushort* vd  = VLw + (lane >> 2) * VROW + (lane & 3) * 8;

    f32x16 acc0, acc1, z16;
    #pragma unroll
    for (int i = 0; i < 16; ++i) { acc0[i] = 0.f; acc1[i] = 0.f; z16[i] = 0.f; }
    float m_run = -1e30f, l_run = 0.f;

    // prologue: stage chunk 0 (private slice, no barrier)
    {
        uint4v p0 = *(const uint4v*)(vs + (size_t)0 * 16 * N_);
        uint4v p1 = *(const uint4v*)(vs + (size_t)1 * 16 * N_);
        uint4v p2 = *(const uint4v*)(vs + (size_t)2 * 16 * N_);
        uint4v p3 = *(const uint4v*)(vs + (size_t)3 * 16 * N_);
        *(uint4v*)(vd + 0 * 16 * VROW) = p0;
        *(uint4v*)(vd + 1 * 16 * VROW) = p1;
        *(uint4v*)(vd + 2 * 16 * VROW) = p2;
        *(uint4v*)(vd + 3 * 16 * VROW) = p3;
    }

    uint4v vr[4];
    #pragma unroll 1
    for (int jc = 0; jc < NCH_; ++jc) {
        if (jc + 1 < NCH_) {   // prefetch next chunk into regs (T14)
            const ushort* vsn = vs + (jc + 1) * CH_;
            #pragma unroll
            for (int e = 0; e < 4; ++e)
                vr[e] = *(const uint4v*)(vsn + (size_t)e * 16 * N_);
        }

        // ---- energy: S^T (32j x 32i) = K_chunk (A) x Q (B), K=16 ----
        const bf16x8 kf = *(const bf16x8*)(kp + (size_t)jc * CH_ * 16);
        f32x16 st = MFMA32(kf, qf, z16);

        // ---- online softmax: lane holds 16 j for query i=l31 ----
        float m_c = st[0];
        #pragma unroll
        for (int i = 1; i < 16; ++i) m_c = fmaxf(m_c, st[i]);
        m_c = fmaxf(m_c, __shfl_xor(m_c, 32));
        if (__any(m_c > m_run + 8.f)) {     // defer-rescale (T13)
            const float m_new = fmaxf(m_run, m_c);
            const float sc = exp2f(m_run - m_new);
            l_run *= sc;
            #pragma unroll
            for (int i = 0; i < 16; ++i) { acc0[i] *= sc; acc1[i] *= sc; }
            m_run = m_new;
        }
        float ps = 0.f;
        #pragma unroll
        for (int i = 0; i < 16; ++i) { st[i] = exp2f(st[i] - m_run); ps += st[i]; }
        ps += __shfl_xor(ps, 32);
        l_run += ps;

        // ---- P -> bf16 PV-fragments fully in-register (T12) ----
        // C/D row map: j = (reg&3) + 8*(reg>>2) + 4h. After the 4 swaps,
        // frag_s covers j = s*16 + h*8 + r for the consuming lane.
        uint X0 = cvtpk(st[0],  st[1]),  X1 = cvtpk(st[2],  st[3]);
        uint Y0 = cvtpk(st[4],  st[5]),  Y1 = cvtpk(st[6],  st[7]);
        uint Z0 = cvtpk(st[8],  st[9]),  Z1 = cvtpk(st[10], st[11]);
        uint W0 = cvtpk(st[12], st[13]), W1 = cvtpk(st[14], st[15]);
        plswap(X0, Y0); plswap(X1, Y1);
        plswap(Z0, W0); plswap(Z1, W1);
        uint4v u0 = {X0, X1, Y0, Y1};
        uint4v u1 = {Z0, Z1, W0, W1};
        const bf16x8 pf0 = __builtin_bit_cast(bf16x8, u0);
        const bf16x8 pf1 = __builtin_bit_cast(bf16x8, u1);

        // ---- PV: O^T[c][i] += V (A: row=c, k=j) x P (B), K=16 x2 ----
        const bf16x8 vf00 = *(const bf16x8*)(VLw + (0 * 32 + l31) * VROW + 0 * 16 + h * 8);
        const bf16x8 vf01 = *(const bf16x8*)(VLw + (0 * 32 + l31) * VROW + 1 * 16 + h * 8);
        const bf16x8 vf10 = *(const bf16x8*)(VLw + (1 * 32 + l31) * VROW + 0 * 16 + h * 8);
        const bf16x8 vf11 = *(const bf16x8*)(VLw + (1 * 32 + l31) * VROW + 1 * 16 + h * 8);
        acc0 = MFMA32(vf00, pf0, acc0);
        acc0 = MFMA32(vf01, pf1, acc0);
        acc1 = MFMA32(vf10, pf0, acc1);
        acc1 = MFMA32(vf11, pf1, acc1);

        // ---- write prefetched chunk (same-wave DS is in-order; safe) ----
        if (jc + 1 < NCH_) {
            #pragma unroll
            for (int e = 0; e < 4; ++e)
                *(uint4v*)(vd + e * 16 * VROW) = vr[e];
        }
    }

    // ---- merge 8 j-partials ----
    if (h == 0) { MC[w * 33 + l31] = m_run; LC[w * 33 + l31] = l_run; }
    __syncthreads();                        // bar0: main loops done, VL dead

    float mp[8];
    #pragma unroll
    for (int p = 0; p < 8; ++p) mp[p] = MC[p * 33 + l31];
    float ms = mp[0];
    #pragma unroll
    for (int p = 1; p < 8; ++p) ms = fmaxf(ms, mp[p]);
    float lsum = 0.f, wt_own = 0.f;
    #pragma unroll
    for (int p = 0; p < 8; ++p) {
        const float wt = exp2f(mp[p] - ms);
        lsum += wt * LC[p * 33 + l31];
        if (p == w) wt_own = wt;
    }
    if (w == 0 && h == 0) IV[l31] = lam[0] / lsum;

    #pragma unroll
    for (int r = 0; r < 16; ++r) {
        const int c = (r & 3) + 8 * (r >> 2) + 4 * h;
        OT[(w * 64 + c) * OTP + l31]        = acc0[r] * wt_own;
        OT[(w * 64 + c + 32) * OTP + l31]   = acc1[r] * wt_own;
    }
    __syncthreads();                        // bar1

    // ---- epilogue: out = sum_p OT[p] * IV + x (coalesced float4) ----
    {
        const int c = t >> 3, sg = t & 7;
        f32x4 o = {0.f, 0.f, 0.f, 0.f};
        #pragma unroll
        for (int p = 0; p < 8; ++p) {
            const f32x4 v = *(const f32x4*)&OT[(p * 64 + c) * OTP + sg * 4];
            o[0] += v[0]; o[1] += v[1]; o[2] += v[2]; o[3] += v[3];
        }
        const size_t off = ((size_t)b * C_ + c) * N_ + i0 + sg * 4;
        const float4 xv = *(const float4*)(x + off);
        float4 res;
        res.x = o[0] * IV[sg * 4 + 0] + xv.x;
        res.y = o[1] * IV[sg * 4 + 1] + xv.y;
        res.z = o[2] * IV[sg * 4 + 2] + xv.z;
        res.w = o[3] * IV[sg * 4 + 3] + xv.w;
        *(float4*)(out + off) = res;
    }
}

extern "C" void kernel_launch(void* const* d_in, const int* in_sizes, int n_in,
                              void* d_out, int out_size, void* d_ws, size_t ws_size,
                              hipStream_t stream)
{
    (void)in_sizes; (void)n_in; (void)out_size; (void)ws_size;
    const float* x    = (const float*)d_in[0];
    const float* xrgb = (const float*)d_in[1];
    const float* Wq   = (const float*)d_in[2];
    const float* bq   = (const float*)d_in[3];
    const float* Wk   = (const float*)d_in[4];
    const float* bk   = (const float*)d_in[5];
    const float* Wv   = (const float*)d_in[6];
    const float* bv   = (const float*)d_in[7];
    const float* lam  = (const float*)d_in[8];
    float* out = (float*)d_out;

    // workspace (bf16): Q 512KB | K 512KB | V 2MB — all fully overwritten
    ushort* Qw = (ushort*)d_ws;                       // [B][N][16]
    ushort* Kw = Qw + (size_t)B_ * N_ * 16;           // [B][N][16]
    ushort* Vw = Kw + (size_t)B_ * N_ * 16;           // [B][C][N]

    qkv_mfma<<<dim3(N_ / 32, B_), 256, 0, stream>>>(
        x, xrgb, Wq, bq, Wk, bk, Wv, bv, Qw, Kw, Vw);

    flash32<<<dim3(512), 512, 0, stream>>>(
        Qw, Kw, Vw, x, lam, out);
}

// Round 8
// 36.795 us; speedup vs baseline: 3.8052x; 1.1369x over previous
//
#include <hip/hip_runtime.h>
#include <hip/hip_bf16.h>
#include <math.h>

#define B_   4
#define C_   64
#define N_   4096
#define L2E  1.4426950408889634f

typedef __attribute__((ext_vector_type(8)))  short bf16x8;
typedef __attribute__((ext_vector_type(4)))  float f32x4;
typedef __attribute__((ext_vector_type(16))) float f32x16;
typedef __attribute__((ext_vector_type(4)))  uint  uint4v;

#define MFMA16(a,b,c) __builtin_amdgcn_mfma_f32_16x16x32_bf16(a,b,c,0,0,0)
#define MFMA32(a,b,c) __builtin_amdgcn_mfma_f32_32x32x16_bf16(a,b,c,0,0,0)

static __device__ inline ushort f2bf(float f) {
    __hip_bfloat16 h = __float2bfloat16(f);
    return *reinterpret_cast<ushort*>(&h);
}
static __device__ inline uint packbf(float a, float b) {
    return (uint)f2bf(a) | ((uint)f2bf(b) << 16);
}
static __device__ inline uint cvtpk(float lo, float hi) {
    uint r;
    asm("v_cvt_pk_bf16_f32 %0, %1, %2" : "=v"(r) : "v"(lo), "v"(hi));
    return r;
}
static __device__ inline void plswap(uint &a, uint &b) {
    asm("v_permlane32_swap_b32 %0, %1" : "+v"(a), "+v"(b));
}
// pairwise max/sum trees over a 16-vec (depth 4, exposes ILP)
static __device__ inline float tmax16(const f32x16 &s) {
    float a0 = fmaxf(s[0], s[1]),  a1 = fmaxf(s[2], s[3]);
    float a2 = fmaxf(s[4], s[5]),  a3 = fmaxf(s[6], s[7]);
    float a4 = fmaxf(s[8], s[9]),  a5 = fmaxf(s[10], s[11]);
    float a6 = fmaxf(s[12], s[13]), a7 = fmaxf(s[14], s[15]);
    a0 = fmaxf(a0, a1); a2 = fmaxf(a2, a3); a4 = fmaxf(a4, a5); a6 = fmaxf(a6, a7);
    return fmaxf(fmaxf(a0, a2), fmaxf(a4, a6));
}
static __device__ inline float tsum16(const f32x16 &s) {
    float a0 = s[0] + s[1],  a1 = s[2] + s[3];
    float a2 = s[4] + s[5],  a3 = s[6] + s[7];
    float a4 = s[8] + s[9],  a5 = s[10] + s[11];
    float a6 = s[12] + s[13], a7 = s[14] + s[15];
    a0 += a1; a2 += a3; a4 += a5; a6 += a7;
    return (a0 + a2) + (a4 + a6);
}

// ---------------- QKV projection: direct-W MFMA, 2-way k-split ----------------
// Q,K: [B][N][16] bf16.  V: fragment-major VT[B][N/16][64 c][16 j] bf16 so the
// flash PV A-fragment is a coalesced 16B/lane global load (no LDS transpose).
__global__ __launch_bounds__(256) void qkv_mfma(
    const float* __restrict__ x, const float* __restrict__ xrgb,
    const float* __restrict__ Wq, const float* __restrict__ bq,
    const float* __restrict__ Wk, const float* __restrict__ bk,
    const float* __restrict__ Wv, const float* __restrict__ bv,
    ushort* __restrict__ Qo, ushort* __restrict__ Ko, ushort* __restrict__ Vo)
{
    __shared__ float BLs[96];
    __shared__ float OP[2][96][33];

    const int t = threadIdx.x, b = blockIdx.y, n0 = blockIdx.x * 32;
    const int w = t >> 6, lane = t & 63, li = lane & 15, g = lane >> 4;
    const int pw = w & 1, cw = w >> 1;

    // X fragments (early issue, f32)
    const int n = n0 + pw * 16 + li;
    const int c0 = cw * 32 + g * 8;
    const float* xb = x    + ((size_t)b * C_ + c0) * N_ + n;
    const float* rb = xrgb + ((size_t)b * C_ + c0) * N_ + n;
    float fx[8], fr[8];
    #pragma unroll
    for (int r = 0; r < 8; ++r) { fx[r] = xb[(size_t)r * N_]; fr[r] = rb[(size_t)r * N_]; }

    // W fragments direct from global: A row = ot*16+li, cols c0..c0+7
    float wf[6][8];
    #pragma unroll
    for (int ot = 0; ot < 6; ++ot) {
        const float* wsrc;
        if (ot == 0)      wsrc = Wq + li * 64 + c0;
        else if (ot == 1) wsrc = Wk + li * 64 + c0;
        else              wsrc = Wv + ((ot - 2) * 16 + li) * 64 + c0;
        const float4 a = *(const float4*)(wsrc);
        const float4 c = *(const float4*)(wsrc + 4);
        wf[ot][0] = a.x; wf[ot][1] = a.y; wf[ot][2] = a.z; wf[ot][3] = a.w;
        wf[ot][4] = c.x; wf[ot][5] = c.y; wf[ot][6] = c.z; wf[ot][7] = c.w;
    }

    if (t < 96)
        BLs[t] = (t < 16) ? bq[t] * L2E : (t < 32 ? bk[t - 16] : bv[t - 32]);

    bf16x8 bxf, brf;
    #pragma unroll
    for (int r = 0; r < 8; ++r) {
        bxf[r] = (short)f2bf(fx[r]);
        brf[r] = (short)f2bf(fr[r]);
    }

    const f32x4 cz = {0.f, 0.f, 0.f, 0.f};
    #pragma unroll
    for (int ot = 0; ot < 6; ++ot) {
        bf16x8 wa;
        const float s = (ot == 0) ? L2E : 1.0f;   // fold log2e into Q
        #pragma unroll
        for (int r = 0; r < 8; ++r) wa[r] = (short)f2bf(wf[ot][r] * s);
        const f32x4 acc = MFMA16(wa, (ot == 0 ? brf : bxf), cz);
        #pragma unroll
        for (int r = 0; r < 4; ++r)
            OP[cw][ot * 16 + g * 4 + r][pw * 16 + li] = acc[r];
    }
    __syncthreads();

    {   // Q and K: 32 px x 8 channel-pairs
        const int p = t >> 3, cp = t & 7;
        const float q0 = OP[0][cp * 2][p]     + OP[1][cp * 2][p]     + BLs[cp * 2];
        const float q1 = OP[0][cp * 2 + 1][p] + OP[1][cp * 2 + 1][p] + BLs[cp * 2 + 1];
        *(uint*)&Qo[(size_t)(b * N_ + n0 + p) * 16 + cp * 2] = packbf(q0, q1);
        const float k0 = OP[0][16 + cp * 2][p]     + OP[1][16 + cp * 2][p]     + BLs[16 + cp * 2];
        const float k1 = OP[0][16 + cp * 2 + 1][p] + OP[1][16 + cp * 2 + 1][p] + BLs[16 + cp * 2 + 1];
        *(uint*)&Ko[(size_t)(b * N_ + n0 + p) * 16 + cp * 2] = packbf(k0, k1);
    }
    {   // V -> VT[b][jt][ch][jin]: 64 ch x 4 pixel-octets
        const int ch = t >> 2, po = (t & 3) * 8;
        const float bs = BLs[32 + ch];
        uint4 o;
        #pragma unroll
        for (int e = 0; e < 4; ++e) {
            const float v0 = OP[0][32 + ch][po + 2 * e]     + OP[1][32 + ch][po + 2 * e]     + bs;
            const float v1 = OP[0][32 + ch][po + 2 * e + 1] + OP[1][32 + ch][po + 2 * e + 1] + bs;
            ((uint*)&o)[e] = packbf(v0, v1);
        }
        const size_t jt = (size_t)b * (N_ / 16) + ((n0 + po) >> 4);
        *(uint4*)&Vo[(jt * 64 + ch) * 16 + (po & 8)] = o;
    }
}

// ---------------- flash attention, 32x32 MFMA, zero-LDS main loop ----------
// 512 thr = 8 waves; wave w owns N/8=512 keys (8 iters of 64 = 2 S-tiles,
// ILP-2 softmax). K fragment: coalesced global. V fragment: coalesced global
// from fragment-major VT (L2-resident). P: in-register cvt_pk+permlane (T12).
// No LDS, no barriers in the main loop; 2-barrier merge tail via OT overlay.
#define JG_   8
#define OTP   36           // OT row pad (floats), 144B rows (16B aligned)
#define SMEM_FL (73728 + 1056 + 1056 + 128)

__global__ __launch_bounds__(512, 4) void flash32(
    const ushort* __restrict__ Qg, const ushort* __restrict__ Kg,
    const ushort* __restrict__ VT, const float* __restrict__ x,
    const float* __restrict__ lam, float* __restrict__ out)
{
    __shared__ __align__(16) char smem[SMEM_FL];
    float*  OT = (float*)smem;                       // [8][64][OTP]  73728B
    float*  MC = (float*)(smem + 73728);             // [8][33]
    float*  LC = (float*)(smem + 73728 + 1056);      // [8][33]
    float*  IV = (float*)(smem + 73728 + 2112);      // [32]

    const int t = threadIdx.x, w = t >> 6, lane = t & 63;
    const int l31 = lane & 31, h = lane >> 5;

    // XCD-locality remap: batch b's 128 blocks land on 2 XCDs (K/V L2-local)
    const int wg = blockIdx.x;                 // grid = 512, 1-D
    const int b  = (wg & 7) >> 1;
    const int it = ((wg >> 3) << 1) | (wg & 1);
    const int i0 = it * 32;

    // Q fragment: B op, col=i=l31, k=c=h*8+r (K=16 exact)
    const bf16x8 qf = *(const bf16x8*)(Qg + ((size_t)(b * N_ + i0 + l31)) * 16 + h * 8);

    const size_t jbase = (size_t)w * (N_ / JG_);
    const ushort* kp = Kg + ((size_t)(b * N_) + jbase + l31) * 16 + h * 8;
    // V fragment base: lane -> c=l31 (+32 for acc1), k-half h; jtile stride 1024
    const ushort* vt = VT + (((size_t)b * (N_ / 16) + jbase / 16) * 64 + l31) * 16 + h * 8;

    f32x16 acc0, acc1, z16;
    #pragma unroll
    for (int i = 0; i < 16; ++i) { acc0[i] = 0.f; acc1[i] = 0.f; z16[i] = 0.f; }
    float m_run = -1e30f, l_loc = 0.f;

    #pragma unroll 1
    for (int it8 = 0; it8 < 8; ++it8) {
        const int j0 = it8 * 64;

        // ---- energy: two 32-key S-tiles (K=16 exact, no padding) ----
        const bf16x8 kf0 = *(const bf16x8*)(kp + (size_t)(j0) * 16);
        const bf16x8 kf1 = *(const bf16x8*)(kp + (size_t)(j0 + 32) * 16);
        f32x16 st0 = MFMA32(kf0, qf, z16);
        f32x16 st1 = MFMA32(kf1, qf, z16);

        // ---- online softmax over 64 keys, ILP-2 trees ----
        float m_c = fmaxf(tmax16(st0), tmax16(st1));
        m_c = fmaxf(m_c, __shfl_xor(m_c, 32));
        if (__any(m_c > m_run + 8.f)) {     // defer-rescale (T13)
            const float m_new = fmaxf(m_run, m_c);
            const float sc = exp2f(m_run - m_new);
            l_loc *= sc;
            #pragma unroll
            for (int i = 0; i < 16; ++i) { acc0[i] *= sc; acc1[i] *= sc; }
            m_run = m_new;
        }
        #pragma unroll
        for (int i = 0; i < 16; ++i) st0[i] = exp2f(st0[i] - m_run);
        #pragma unroll
        for (int i = 0; i < 16; ++i) st1[i] = exp2f(st1[i] - m_run);
        l_loc += tsum16(st0) + tsum16(st1);

        // ---- P -> bf16 PV-fragments in-register (T12, validated R7) ----
        uint A0 = cvtpk(st0[0],  st0[1]),  A1 = cvtpk(st0[2],  st0[3]);
        uint B0 = cvtpk(st0[4],  st0[5]),  B1 = cvtpk(st0[6],  st0[7]);
        uint C0 = cvtpk(st0[8],  st0[9]),  C1 = cvtpk(st0[10], st0[11]);
        uint D0 = cvtpk(st0[12], st0[13]), D1 = cvtpk(st0[14], st0[15]);
        plswap(A0, B0); plswap(A1, B1); plswap(C0, D0); plswap(C1, D1);
        uint E0 = cvtpk(st1[0],  st1[1]),  E1 = cvtpk(st1[2],  st1[3]);
        uint F0 = cvtpk(st1[4],  st1[5]),  F1 = cvtpk(st1[6],  st1[7]);
        uint G0 = cvtpk(st1[8],  st1[9]),  G1 = cvtpk(st1[10], st1[11]);
        uint H0 = cvtpk(st1[12], st1[13]), H1 = cvtpk(st1[14], st1[15]);
        plswap(E0, F0); plswap(E1, F1); plswap(G0, H0); plswap(G1, H1);
        uint4v u0 = {A0, A1, B0, B1}, u1 = {C0, C1, D0, D1};
        uint4v u2 = {E0, E1, F0, F1}, u3 = {G0, G1, H0, H1};
        const bf16x8 pf0 = __builtin_bit_cast(bf16x8, u0);
        const bf16x8 pf1 = __builtin_bit_cast(bf16x8, u1);
        const bf16x8 pf2 = __builtin_bit_cast(bf16x8, u2);
        const bf16x8 pf3 = __builtin_bit_cast(bf16x8, u3);

        // ---- PV: coalesced V fragments straight from L2 (VT layout) ----
        const ushort* vtj = vt + (size_t)(j0 >> 4) * 1024;
        const bf16x8 va0 = *(const bf16x8*)(vtj);
        const bf16x8 va1 = *(const bf16x8*)(vtj + 1024);
        const bf16x8 va2 = *(const bf16x8*)(vtj + 2048);
        const bf16x8 va3 = *(const bf16x8*)(vtj + 3072);
        acc0 = MFMA32(va0, pf0, acc0);
        acc0 = MFMA32(va1, pf1, acc0);
        acc0 = MFMA32(va2, pf2, acc0);
        acc0 = MFMA32(va3, pf3, acc0);
        const bf16x8 vb0 = *(const bf16x8*)(vtj + 512);
        const bf16x8 vb1 = *(const bf16x8*)(vtj + 1536);
        const bf16x8 vb2 = *(const bf16x8*)(vtj + 2560);
        const bf16x8 vb3 = *(const bf16x8*)(vtj + 3584);
        acc1 = MFMA32(vb0, pf0, acc1);
        acc1 = MFMA32(vb1, pf1, acc1);
        acc1 = MFMA32(vb2, pf2, acc1);
        acc1 = MFMA32(vb3, pf3, acc1);
    }
    const float l_run = l_loc + __shfl_xor(l_loc, 32);

    // ---- merge 8 j-partials ----
    if (h == 0) { MC[w * 33 + l31] = m_run; LC[w * 33 + l31] = l_run; }
    __syncthreads();                        // bar0: main loops done

    float mp[8];
    #pragma unroll
    for (int p = 0; p < 8; ++p) mp[p] = MC[p * 33 + l31];
    float ms = mp[0];
    #pragma unroll
    for (int p = 1; p < 8; ++p) ms = fmaxf(ms, mp[p]);
    float lsum = 0.f, wt_own = 0.f;
    #pragma unroll
    for (int p = 0; p < 8; ++p) {
        const float wt = exp2f(mp[p] - ms);
        lsum += wt * LC[p * 33 + l31];
        if (p == w) wt_own = wt;
    }
    if (w == 0 && h == 0) IV[l31] = lam[0] / lsum;

    #pragma unroll
    for (int r = 0; r < 16; ++r) {
        const int c = (r & 3) + 8 * (r >> 2) + 4 * h;
        OT[(w * 64 + c) * OTP + l31]      = acc0[r] * wt_own;
        OT[(w * 64 + c + 32) * OTP + l31] = acc1[r] * wt_own;
    }
    __syncthreads();                        // bar1

    // ---- epilogue: out = sum_p OT[p] * IV + x (coalesced float4) ----
    {
        const int c = t >> 3, sg = t & 7;
        f32x4 o = {0.f, 0.f, 0.f, 0.f};
        #pragma unroll
        for (int p = 0; p < 8; ++p) {
            const f32x4 v = *(const f32x4*)&OT[(p * 64 + c) * OTP + sg * 4];
            o[0] += v[0]; o[1] += v[1]; o[2] += v[2]; o[3] += v[3];
        }
        const size_t off = ((size_t)b * C_ + c) * N_ + i0 + sg * 4;
        const float4 xv = *(const float4*)(x + off);
        float4 res;
        res.x = o[0] * IV[sg * 4 + 0] + xv.x;
        res.y = o[1] * IV[sg * 4 + 1] + xv.y;
        res.z = o[2] * IV[sg * 4 + 2] + xv.z;
        res.w = o[3] * IV[sg * 4 + 3] + xv.w;
        *(float4*)(out + off) = res;
    }
}

extern "C" void kernel_launch(void* const* d_in, const int* in_sizes, int n_in,
                              void* d_out, int out_size, void* d_ws, size_t ws_size,
                              hipStream_t stream)
{
    (void)in_sizes; (void)n_in; (void)out_size; (void)ws_size;
    const float* x    = (const float*)d_in[0];
    const float* xrgb = (const float*)d_in[1];
    const float* Wq   = (const float*)d_in[2];
    const float* bq   = (const float*)d_in[3];
    const float* Wk   = (const float*)d_in[4];
    const float* bk   = (const float*)d_in[5];
    const float* Wv   = (const float*)d_in[6];
    const float* bv   = (const float*)d_in[7];
    const float* lam  = (const float*)d_in[8];
    float* out = (float*)d_out;

    // workspace (bf16): Q 512KB | K 512KB | VT 2MB — all fully overwritten
    ushort* Qw = (ushort*)d_ws;                       // [B][N][16]
    ushort* Kw = Qw + (size_t)B_ * N_ * 16;           // [B][N][16]
    ushort* Vw = Kw + (size_t)B_ * N_ * 16;           // VT[B][N/16][64][16]

    qkv_mfma<<<dim3(N_ / 32, B_), 256, 0, stream>>>(
        x, xrgb, Wq, bq, Wk, bk, Wv, bv, Qw, Kw, Vw);

    flash32<<<dim3(512), 512, 0, stream>>>(
        Qw, Kw, Vw, x, lam, out);
}